// Round 5
// baseline (481.347 us; speedup 1.0000x reference)
//
#include <hip/hip_runtime.h>
#include <hip/hip_bf16.h>

typedef unsigned short u16t;
typedef unsigned int   u32t;
typedef float  f32x4 __attribute__((ext_vector_type(4)));
typedef short  s16x8 __attribute__((ext_vector_type(8)));
typedef unsigned int u32x4 __attribute__((ext_vector_type(4)));
typedef float  f4 __attribute__((ext_vector_type(4)));

#define BB 2
#define TT 2048
#define CC 2048
#define HH 16
#define KVHN 4
#define DD 128
#define EPSV 1.1920929e-07f
#define SCALE 0.08838834764831845f
#define MFIX 12.0f   // fixed softmax max: |q.k|*SCALE <= sqrt(128)*(1+bf16 err) < 11.5

__device__ __forceinline__ float b2f(u16t u){ union{u32t i; float f;} x; x.i=((u32t)u)<<16; return x.f; }
__device__ __forceinline__ u16t f2b(float f){ union{float f; u32t i;} x; x.f=f; u32t r = x.i + 0x7fffu + ((x.i>>16)&1u); return (u16t)(r>>16); }
__device__ __forceinline__ u32t pk2(float a, float b){
    __hip_bfloat162 h = __float22bfloat162_rn(make_float2(a,b));
    u32t r; __builtin_memcpy(&r,&h,4); return r;
}
__device__ __forceinline__ s16x8 ldf(const u16t* p){ s16x8 r; __builtin_memcpy(&r,p,16); return r; }
__device__ __forceinline__ void st16(u16t* p, u32x4 v){ __builtin_memcpy(p,&v,16); }
__device__ __forceinline__ u32x4 ldg16(const u16t* p){ u32x4 r; __builtin_memcpy(&r,p,16); return r; }

// async global->LDS, 16B per lane; HW LDS dest = wave-uniform base + lane*16
// (we pass base + lane*8 elems, which equals that under either semantics)
typedef const __attribute__((address_space(1))) unsigned int ga_u32;
typedef __attribute__((address_space(3))) unsigned int ls_u32;
__device__ __forceinline__ void gl16(const u16t* g, u16t* l) {
    __builtin_amdgcn_global_load_lds((ga_u32*)(unsigned long long)(g),
                                     (ls_u32*)(unsigned int)(unsigned long long)(l),
                                     16, 0, 0);
}

// ---------------- Kernel 0: fp32 -> bf16 conversion ----------------
// segments (in 8-elem groups): x 1048576 | wq 524288 | wk 131072 | wv 131072 | wo 524288
__global__ __launch_bounds__(256) void cvt_kernel(
    const float* __restrict__ x,  const float* __restrict__ wq,
    const float* __restrict__ wk, const float* __restrict__ wv,
    const float* __restrict__ wo,
    u16t* __restrict__ xb, u16t* __restrict__ wqb, u16t* __restrict__ wkb,
    u16t* __restrict__ wvb, u16t* __restrict__ wob)
{
    size_t g = (size_t)blockIdx.x * 256 + threadIdx.x;
    const float* src; u16t* dst; size_t off;
    if      (g < 1048576) { src = x;  dst = xb;  off = g; }
    else if (g < 1572864) { src = wq; dst = wqb; off = g - 1048576; }
    else if (g < 1703936) { src = wk; dst = wkb; off = g - 1572864; }
    else if (g < 1835008) { src = wv; dst = wvb; off = g - 1703936; }
    else                  { src = wo; dst = wob; off = g - 1835008; }
    f4 a = *(const f4*)(src + off*8);
    f4 b = *(const f4*)(src + off*8 + 4);
    u32x4 o = { pk2(a[0],a[1]), pk2(a[2],a[3]), pk2(b[0],b[1]), pk2(b[2],b[3]) };
    st16(dst + off*8, o);
}

// ---------------- Kernel 1: QKV GEMM (MFMA, fragment-identity LDS) + RoPE + RMSNorm ----------------
// C = xb @ W^T, W rows = [Wq;Wk;Wv] bf16. Tile 128x128, BK=32.
// LDS layout: 8 fragment blocks per operand; block bl holds rows bl*16..bl*16+15,
// lane (quad,l15) owns [row=bl*16+l15][col=quad*8..+7] at base+bl*1024B+lane*16B.
__global__ __launch_bounds__(256) void qkv_kernel(
    const u16t* __restrict__ xb, const u16t* __restrict__ wqb,
    const u16t* __restrict__ wkb, const u16t* __restrict__ wvb,
    const float* __restrict__ cosp, const float* __restrict__ sinp,
    u16t* __restrict__ qws, u16t* __restrict__ kws, u16t* __restrict__ vtw)
{
    __shared__ u16t lds[16896];   // staging As+Bs (8192 elems) / epilogue Cs (16896 elems)
    u16t* As = lds;               // 8 blocks x 512 elems
    u16t* Bs = lds + 4096;

    const int tid = threadIdx.x;
    const int w = tid>>6, lane = tid&63, quad = lane>>4, l15 = lane&15;
    const int wm = (w>>1)*64, wn = (w&1)*64;
    const int m0 = blockIdx.x*128;
    const int n0 = blockIdx.y*128;

    int type, head; const u16t* W;
    if (n0 < 2048)      { type=0; head = n0>>7;        W = wqb + (size_t)n0*CC; }
    else if (n0 < 2560) { type=1; head = (n0-2048)>>7; W = wkb + (size_t)(n0-2048)*CC; }
    else                { type=2; head = (n0-2560)>>7; W = wvb + (size_t)(n0-2560)*CC; }

    // staging: wave w stages A blocks {w, w+4}, B blocks {w, w+4}
    const u16t* gA0 = xb + (size_t)(m0 + w*16 + l15)*CC + quad*8;
    const u16t* gA1 = xb + (size_t)(m0 + 64 + w*16 + l15)*CC + quad*8;
    const u16t* gB0 = W + (size_t)(w*16 + l15)*CC + quad*8;
    const u16t* gB1 = W + (size_t)(64 + w*16 + l15)*CC + quad*8;
    u16t* lA0 = &As[w*512 + lane*8];
    u16t* lA1 = &As[(w+4)*512 + lane*8];
    u16t* lB0 = &Bs[w*512 + lane*8];
    u16t* lB1 = &Bs[(w+4)*512 + lane*8];

    f32x4 acc[4][4];
    #pragma unroll
    for (int i=0;i<4;++i)
        #pragma unroll
        for (int j=0;j<4;++j)
            #pragma unroll
            for (int r=0;r<4;++r) acc[i][j][r] = 0.f;

    for (int k0=0;k0<CC;k0+=32) {
        __syncthreads();
        gl16(gA0 + k0, lA0);
        gl16(gA1 + k0, lA1);
        gl16(gB0 + k0, lB0);
        gl16(gB1 + k0, lB1);
        __syncthreads();
        s16x8 af[4], bf[4];
        #pragma unroll
        for (int mi=0;mi<4;++mi) af[mi] = ldf(&As[((w>>1)*4 + mi)*512 + lane*8]);
        #pragma unroll
        for (int ni=0;ni<4;++ni) bf[ni] = ldf(&Bs[((w&1)*4 + ni)*512 + lane*8]);
        #pragma unroll
        for (int mi=0;mi<4;++mi)
            #pragma unroll
            for (int ni=0;ni<4;++ni)
                acc[mi][ni] = __builtin_amdgcn_mfma_f32_16x16x32_bf16(af[mi], bf[ni], acc[mi][ni], 0,0,0);
    }

    const int bb = m0>>11, tb0 = m0&2047;

    if (type==2) {
        // V: store transposed vt[b][kvh][d][t]
        u16t* vb = vtw + (size_t)(bb*KVHN+head)*DD*TT;
        #pragma unroll
        for (int mi=0;mi<4;++mi){
            int t = tb0 + wm + mi*16 + quad*4;
            #pragma unroll
            for (int ni=0;ni<4;++ni){
                int d = wn + ni*16 + l15;
                u16t o[4];
                #pragma unroll
                for (int r=0;r<4;++r) o[r] = f2b(acc[mi][ni][r]);
                __builtin_memcpy(vb + (size_t)d*TT + t, o, 8);
            }
        }
    } else {
        __syncthreads();
        u16t* Cs = lds;   // [128][132] bf16
        #pragma unroll
        for (int mi=0;mi<4;++mi)
            #pragma unroll
            for (int ni=0;ni<4;++ni)
                #pragma unroll
                for (int r=0;r<4;++r)
                    Cs[(wm+mi*16+quad*4+r)*132 + wn+ni*16+l15] = f2b(acc[mi][ni][r]);
        __syncthreads();
        const int r = tid>>1, g = tid&1;
        const int t = tb0 + r;
        float vals[64]; float ss=0.f;
        const f4* cp = (const f4*)(cosp + t*64);
        const f4* sp = (const f4*)(sinp + t*64);
        #pragma unroll
        for (int j4=0;j4<16;++j4){
            f4 cs = cp[j4], sn = sp[j4];
            #pragma unroll
            for (int u=0;u<4;++u){
                int j = j4*4+u;
                float z1 = b2f(Cs[r*132 + j]);
                float z2 = b2f(Cs[r*132 + 64 + j]);
                float zo = g ? (z2*cs[u] - z1*sn[u]) : (z1*cs[u] + z2*sn[u]);
                vals[j]=zo; ss += zo*zo;
            }
        }
        ss += __shfl_xor(ss, 1);
        float rms = rsqrtf(ss*(1.f/128.f)+EPSV);
        u16t* dst = (type==0 ? qws + ((size_t)(bb*HH+head)*TT + t)*DD
                             : kws + ((size_t)(bb*KVHN+head)*TT + t)*DD) + g*64;
        #pragma unroll
        for (int j=0;j<64;j+=8){
            u32x4 o = { pk2(vals[j]*rms,   vals[j+1]*rms), pk2(vals[j+2]*rms, vals[j+3]*rms),
                        pk2(vals[j+4]*rms, vals[j+5]*rms), pk2(vals[j+6]*rms, vals[j+7]*rms) };
            st16(dst+j, o);
        }
    }
}

// ---------------- Kernel 2: causal flash attention (MFMA, fixed-max softmax) ----------------
// Fragment-identity LDS for K (16 blocks: kq*4+ni) and V^T (16 blocks: ks*8+n8).
// Q fragments loaded directly from global (no LDS stage).
__global__ __launch_bounds__(256) void attn_kernel(
    const u16t* __restrict__ qws, const u16t* __restrict__ kws,
    const u16t* __restrict__ vtw, u16t* __restrict__ yws)
{
    __shared__ u16t lds[25600];       // 51200 B
    u16t* Ks = lds;                   // 16 blocks x 512
    u16t* Vt = lds + 8192;            // 16 blocks x 512
    u16t* Ps = lds + 16384;           // [128][72] per-wave P slices

    const int tid = threadIdx.x;
    const int w = tid>>6, lane = tid&63, quad = lane>>4, l15 = lane&15;
    const int qti = 15 - blockIdx.x;  // long blocks dispatch first
    const int q0 = qti*128;
    const int h = blockIdx.y, b = blockIdx.z, kvh = h>>2;

    const u16t* qb = qws + ((size_t)(b*HH+h)*TT + q0)*DD;
    const u16t* kb = kws + (size_t)(b*KVHN+kvh)*TT*DD;
    const u16t* vb = vtw + (size_t)(b*KVHN+kvh)*DD*TT;

    // Q fragments straight from global
    s16x8 qf[2][4];
    #pragma unroll
    for (int mi=0;mi<2;++mi)
        #pragma unroll
        for (int kq=0;kq<4;++kq)
            qf[mi][kq] = ldf(qb + (size_t)(w*32+mi*16+l15)*DD + kq*32 + quad*8);

    // staging source pointers: wave w stages K blocks (kq=w, ni=u) and V blocks bl=4w+u
    const u16t* gK[4]; u16t* lK[4];
    const u16t* gV[4]; u16t* lV[4];
    #pragma unroll
    for (int u=0;u<4;++u){
        gK[u] = kb + (size_t)(u*16 + l15)*DD + w*32 + quad*8;   // + (k0)*DD per iter
        lK[u] = &Ks[(w*4+u)*512 + lane*8];
        int bl = w*4+u, ks = bl>>3, n8 = bl&7;
        gV[u] = vb + (size_t)(n8*16 + l15)*TT + ks*32 + quad*8; // + k0 per iter
        lV[u] = &Vt[bl*512 + lane*8];
    }

    f32x4 o_[2][8];
    float l_[2][4];
    #pragma unroll
    for (int mi=0;mi<2;++mi){
        #pragma unroll
        for (int r=0;r<4;++r) l_[mi][r] = 0.f;
        #pragma unroll
        for (int n8=0;n8<8;++n8)
            #pragma unroll
            for (int r=0;r<4;++r) o_[mi][n8][r] = 0.f;
    }

    const int nkt = (qti+1)*2;
    const int qwbase = q0 + w*32;

    for (int kt=0; kt<nkt; ++kt){
        const int k0 = kt*64;
        __syncthreads();
        #pragma unroll
        for (int u=0;u<4;++u){
            gl16(gK[u] + (size_t)k0*DD, lK[u]);
            gl16(gV[u] + k0,            lV[u]);
        }
        __syncthreads();
        if (k0 > qwbase + 31) continue;   // wave-uniform: fully masked for this wave

        // S = Q K^T
        f32x4 s[2][4];
        #pragma unroll
        for (int mi=0;mi<2;++mi)
            #pragma unroll
            for (int ni=0;ni<4;++ni)
                #pragma unroll
                for (int r=0;r<4;++r) s[mi][ni][r] = 0.f;
        #pragma unroll
        for (int kq=0;kq<4;++kq){
            s16x8 kf[4];
            #pragma unroll
            for (int ni=0;ni<4;++ni) kf[ni] = ldf(&Ks[(kq*4+ni)*512 + lane*8]);
            #pragma unroll
            for (int mi=0;mi<2;++mi)
                #pragma unroll
                for (int ni=0;ni<4;++ni)
                    s[mi][ni] = __builtin_amdgcn_mfma_f32_16x16x32_bf16(qf[mi][kq], kf[ni], s[mi][ni], 0,0,0);
        }

        // fixed-max softmax: p = exp(s*SCALE - MFIX); l accumulates per-lane partials
        const bool need_mask = (k0 + 63) > qwbase;
        #pragma unroll
        for (int mi=0;mi<2;++mi){
            const int qrow = qwbase + mi*16 + quad*4;
            #pragma unroll
            for (int ni=0;ni<4;++ni){
                const int kcol = k0 + ni*16 + l15;
                #pragma unroll
                for (int r=0;r<4;++r){
                    float p = __expf(__builtin_fmaf(s[mi][ni][r], SCALE, -MFIX));
                    if (need_mask && kcol > qrow + r) p = 0.f;
                    l_[mi][r] += p;
                    Ps[(w*32+mi*16+quad*4+r)*72 + ni*16 + l15] = f2b(p);
                }
            }
        }

        // O += P V  (same-wave LDS round-trip; DS ops in-order, no barrier)
        #pragma unroll
        for (int ks=0;ks<2;++ks){
            s16x8 pf[2];
            #pragma unroll
            for (int mi=0;mi<2;++mi)
                pf[mi] = ldf(&Ps[(w*32+mi*16+l15)*72 + ks*32 + quad*8]);
            #pragma unroll
            for (int n8=0;n8<8;++n8){
                s16x8 vf = ldf(&Vt[(ks*8+n8)*512 + lane*8]);
                #pragma unroll
                for (int mi=0;mi<2;++mi)
                    o_[mi][n8] = __builtin_amdgcn_mfma_f32_16x16x32_bf16(pf[mi], vf, o_[mi][n8], 0,0,0);
            }
        }
    }

    // epilogue: reduce l across the 16 col-lanes, normalize, store y[b][t][h*128+d]
    #pragma unroll
    for (int mi=0;mi<2;++mi){
        const int qrow = q0 + w*32 + mi*16 + quad*4;
        float inv[4];
        #pragma unroll
        for (int r=0;r<4;++r){
            float lt = l_[mi][r];
            lt += __shfl_xor(lt,1,16);
            lt += __shfl_xor(lt,2,16);
            lt += __shfl_xor(lt,4,16);
            lt += __shfl_xor(lt,8,16);
            inv[r] = 1.f/lt;
        }
        #pragma unroll
        for (int n8=0;n8<8;++n8)
            #pragma unroll
            for (int r=0;r<4;++r)
                yws[((size_t)(b*TT + qrow + r))*2048 + h*DD + n8*16 + l15] = f2b(o_[mi][n8][r]*inv[r]);
    }
}

// ---------------- Kernel 3: output projection (MFMA, fragment-identity LDS) ----------------
__global__ __launch_bounds__(256) void oproj_kernel(
    const u16t* __restrict__ y, const u16t* __restrict__ wob, float* __restrict__ out)
{
    __shared__ u16t lds[8192];
    u16t* As = lds;
    u16t* Bs = lds + 4096;

    const int tid = threadIdx.x;
    const int w = tid>>6, lane = tid&63, quad = lane>>4, l15 = lane&15;
    const int wm = (w>>1)*64, wn = (w&1)*64;
    const int m0 = blockIdx.x*128;
    const int n0 = blockIdx.y*128;

    const u16t* gA0 = y + (size_t)(m0 + w*16 + l15)*CC + quad*8;
    const u16t* gA1 = y + (size_t)(m0 + 64 + w*16 + l15)*CC + quad*8;
    const u16t* gB0 = wob + (size_t)(n0 + w*16 + l15)*CC + quad*8;
    const u16t* gB1 = wob + (size_t)(n0 + 64 + w*16 + l15)*CC + quad*8;
    u16t* lA0 = &As[w*512 + lane*8];
    u16t* lA1 = &As[(w+4)*512 + lane*8];
    u16t* lB0 = &Bs[w*512 + lane*8];
    u16t* lB1 = &Bs[(w+4)*512 + lane*8];

    f32x4 acc[4][4];
    #pragma unroll
    for (int i=0;i<4;++i)
        #pragma unroll
        for (int j=0;j<4;++j)
            #pragma unroll
            for (int r=0;r<4;++r) acc[i][j][r] = 0.f;

    for (int k0=0;k0<CC;k0+=32) {
        __syncthreads();
        gl16(gA0 + k0, lA0);
        gl16(gA1 + k0, lA1);
        gl16(gB0 + k0, lB0);
        gl16(gB1 + k0, lB1);
        __syncthreads();
        s16x8 af[4], bf[4];
        #pragma unroll
        for (int mi=0;mi<4;++mi) af[mi] = ldf(&As[((w>>1)*4 + mi)*512 + lane*8]);
        #pragma unroll
        for (int ni=0;ni<4;++ni) bf[ni] = ldf(&Bs[((w&1)*4 + ni)*512 + lane*8]);
        #pragma unroll
        for (int mi=0;mi<4;++mi)
            #pragma unroll
            for (int ni=0;ni<4;++ni)
                acc[mi][ni] = __builtin_amdgcn_mfma_f32_16x16x32_bf16(af[mi], bf[ni], acc[mi][ni], 0,0,0);
    }

    #pragma unroll
    for (int mi=0;mi<4;++mi){
        const int m = m0 + wm + mi*16 + quad*4;
        #pragma unroll
        for (int ni=0;ni<4;++ni){
            const int n = n0 + wn + ni*16 + l15;
            #pragma unroll
            for (int r=0;r<4;++r)
                out[(size_t)(m+r)*CC + n] = acc[mi][ni][r];
        }
    }
}

extern "C" void kernel_launch(void* const* d_in, const int* in_sizes, int n_in,
                              void* d_out, int out_size, void* d_ws, size_t ws_size,
                              hipStream_t stream) {
    const float* x    = (const float*)d_in[0];
    const float* cosp = (const float*)d_in[1];
    const float* sinp = (const float*)d_in[2];
    const float* Wq   = (const float*)d_in[3];
    const float* Wk   = (const float*)d_in[4];
    const float* Wv   = (const float*)d_in[5];
    const float* Wo   = (const float*)d_in[6];

    u16t* ws  = (u16t*)d_ws;
    u16t* xb  = ws;                          // 8388608 elems (aliased by yws after qkv)
    u16t* wqb = xb  + 8388608;               // 4194304
    u16t* wkb = wqb + 4194304;               // 1048576
    u16t* wvb = wkb + 1048576;               // 1048576
    u16t* wob = wvb + 1048576;               // 4194304
    u16t* qws = wob + 4194304;               // 8388608
    u16t* kws = qws + 8388608;               // 2097152
    u16t* vtw = kws + 2097152;               // 2097152
    u16t* yws = xb;                          // alias: xb dead after qkv_kernel
    float* out = (float*)d_out;

    cvt_kernel<<<dim3(9216), 256, 0, stream>>>(x, Wq, Wk, Wv, Wo, xb, wqb, wkb, wvb, wob);
    qkv_kernel<<<dim3(32, 24), 256, 0, stream>>>(xb, wqb, wkb, wvb, cosp, sinp, qws, kws, vtw);
    attn_kernel<<<dim3(16, 16, 2), 256, 0, stream>>>(qws, kws, vtw, yws);
    oproj_kernel<<<dim3(32, 16), 256, 0, stream>>>(yws, wob, out);
}

// Round 6
// 436.849 us; speedup vs baseline: 1.1019x; 1.1019x over previous
//
#include <hip/hip_runtime.h>
#include <hip/hip_bf16.h>

typedef unsigned short u16t;
typedef unsigned int   u32t;
typedef float  f32x4 __attribute__((ext_vector_type(4)));
typedef short  s16x8 __attribute__((ext_vector_type(8)));
typedef unsigned int u32x4 __attribute__((ext_vector_type(4)));
typedef float  f4 __attribute__((ext_vector_type(4)));

#define BB 2
#define TT 2048
#define CC 2048
#define HH 16
#define KVHN 4
#define DD 128
#define EPSV 1.1920929e-07f
#define SCALE 0.08838834764831845f
#define MFIX 12.0f   // fixed softmax max: |q.k|*SCALE <= sqrt(128)*(1+bf16 err) < 11.5

__device__ __forceinline__ float b2f(u16t u){ union{u32t i; float f;} x; x.i=((u32t)u)<<16; return x.f; }
__device__ __forceinline__ u16t f2b(float f){ union{float f; u32t i;} x; x.f=f; u32t r = x.i + 0x7fffu + ((x.i>>16)&1u); return (u16t)(r>>16); }
__device__ __forceinline__ u32t pk2(float a, float b){
    __hip_bfloat162 h = __float22bfloat162_rn(make_float2(a,b));
    u32t r; __builtin_memcpy(&r,&h,4); return r;
}
__device__ __forceinline__ s16x8 ldf(const u16t* p){ s16x8 r; __builtin_memcpy(&r,p,16); return r; }
__device__ __forceinline__ void st16(u16t* p, u32x4 v){ __builtin_memcpy(p,&v,16); }

// async global->LDS, 16B per lane; HW LDS dest = wave-uniform base + lane*16
typedef const __attribute__((address_space(1))) unsigned int ga_u32;
typedef __attribute__((address_space(3))) unsigned int ls_u32;
__device__ __forceinline__ void gl16(const u16t* g, u16t* l) {
    __builtin_amdgcn_global_load_lds((ga_u32*)(unsigned long long)(g),
                                     (ls_u32*)(unsigned int)(unsigned long long)(l),
                                     16, 0, 0);
}

// ---------------- Kernel 0: fp32 -> bf16 conversion ----------------
// segments (in 8-elem groups): x 1048576 | wq 524288 | wk 131072 | wv 131072 | wo 524288
__global__ __launch_bounds__(256) void cvt_kernel(
    const float* __restrict__ x,  const float* __restrict__ wq,
    const float* __restrict__ wk, const float* __restrict__ wv,
    const float* __restrict__ wo,
    u16t* __restrict__ xb, u16t* __restrict__ wqb, u16t* __restrict__ wkb,
    u16t* __restrict__ wvb, u16t* __restrict__ wob)
{
    size_t g = (size_t)blockIdx.x * 256 + threadIdx.x;
    const float* src; u16t* dst; size_t off;
    if      (g < 1048576) { src = x;  dst = xb;  off = g; }
    else if (g < 1572864) { src = wq; dst = wqb; off = g - 1048576; }
    else if (g < 1703936) { src = wk; dst = wkb; off = g - 1572864; }
    else if (g < 1835008) { src = wv; dst = wvb; off = g - 1703936; }
    else                  { src = wo; dst = wob; off = g - 1835008; }
    f4 a = *(const f4*)(src + off*8);
    f4 b = *(const f4*)(src + off*8 + 4);
    u32x4 o = { pk2(a[0],a[1]), pk2(a[2],a[3]), pk2(b[0],b[1]), pk2(b[2],b[3]) };
    st16(dst + off*8, o);
}

// ---------------- Kernel 1: QKV GEMM (MFMA, fragment-identity LDS) + RoPE + RMSNorm ----------------
// C = xb @ W^T, W rows = [Wq;Wk;Wv] bf16. Tile 128x128, BK=32.
// __launch_bounds__(256,3): keep VGPR under the 170 cliff -> 3 blocks/CU (r5 hit 180 -> 2/CU).
__global__ __launch_bounds__(256,3) void qkv_kernel(
    const u16t* __restrict__ xb, const u16t* __restrict__ wqb,
    const u16t* __restrict__ wkb, const u16t* __restrict__ wvb,
    const float* __restrict__ cosp, const float* __restrict__ sinp,
    u16t* __restrict__ qws, u16t* __restrict__ kws, u16t* __restrict__ vtw)
{
    __shared__ u16t lds[16896];   // staging As+Bs (8192 elems) / epilogue Cs (16896 elems)
    u16t* As = lds;               // 8 fragment blocks x 512 elems
    u16t* Bs = lds + 4096;

    const int tid = threadIdx.x;
    const int w = tid>>6, lane = tid&63, quad = lane>>4, l15 = lane&15;
    const int wm = (w>>1)*64, wn = (w&1)*64;
    const int m0 = blockIdx.x*128;
    const int n0 = blockIdx.y*128;

    int type, head; const u16t* W;
    if (n0 < 2048)      { type=0; head = n0>>7;        W = wqb + (size_t)n0*CC; }
    else if (n0 < 2560) { type=1; head = (n0-2048)>>7; W = wkb + (size_t)(n0-2048)*CC; }
    else                { type=2; head = (n0-2560)>>7; W = wvb + (size_t)(n0-2560)*CC; }

    // staging: wave w stages A blocks {w, w+4}, B blocks {w, w+4}
    const u16t* gA0 = xb + (size_t)(m0 + w*16 + l15)*CC + quad*8;
    const u16t* gA1 = xb + (size_t)(m0 + 64 + w*16 + l15)*CC + quad*8;
    const u16t* gB0 = W + (size_t)(w*16 + l15)*CC + quad*8;
    const u16t* gB1 = W + (size_t)(64 + w*16 + l15)*CC + quad*8;
    u16t* lA0 = &As[w*512 + lane*8];
    u16t* lA1 = &As[(w+4)*512 + lane*8];
    u16t* lB0 = &Bs[w*512 + lane*8];
    u16t* lB1 = &Bs[(w+4)*512 + lane*8];

    f32x4 acc[4][4];
    #pragma unroll
    for (int i=0;i<4;++i)
        #pragma unroll
        for (int j=0;j<4;++j)
            #pragma unroll
            for (int r=0;r<4;++r) acc[i][j][r] = 0.f;

    for (int k0=0;k0<CC;k0+=32) {
        __syncthreads();
        gl16(gA0 + k0, lA0);
        gl16(gA1 + k0, lA1);
        gl16(gB0 + k0, lB0);
        gl16(gB1 + k0, lB1);
        __syncthreads();
        s16x8 af[4], bf[4];
        #pragma unroll
        for (int mi=0;mi<4;++mi) af[mi] = ldf(&As[((w>>1)*4 + mi)*512 + lane*8]);
        #pragma unroll
        for (int ni=0;ni<4;++ni) bf[ni] = ldf(&Bs[((w&1)*4 + ni)*512 + lane*8]);
        #pragma unroll
        for (int mi=0;mi<4;++mi)
            #pragma unroll
            for (int ni=0;ni<4;++ni)
                acc[mi][ni] = __builtin_amdgcn_mfma_f32_16x16x32_bf16(af[mi], bf[ni], acc[mi][ni], 0,0,0);
    }

    const int bb = m0>>11, tb0 = m0&2047;

    if (type==2) {
        // V: store transposed vt[b][kvh][d][t]
        u16t* vb = vtw + (size_t)(bb*KVHN+head)*DD*TT;
        #pragma unroll
        for (int mi=0;mi<4;++mi){
            int t = tb0 + wm + mi*16 + quad*4;
            #pragma unroll
            for (int ni=0;ni<4;++ni){
                int d = wn + ni*16 + l15;
                u16t o[4];
                #pragma unroll
                for (int r=0;r<4;++r) o[r] = f2b(acc[mi][ni][r]);
                __builtin_memcpy(vb + (size_t)d*TT + t, o, 8);
            }
        }
    } else {
        __syncthreads();
        u16t* Cs = lds;   // [128][132] bf16
        #pragma unroll
        for (int mi=0;mi<4;++mi)
            #pragma unroll
            for (int ni=0;ni<4;++ni)
                #pragma unroll
                for (int r=0;r<4;++r)
                    Cs[(wm+mi*16+quad*4+r)*132 + wn+ni*16+l15] = f2b(acc[mi][ni][r]);
        __syncthreads();
        const int r = tid>>1, g = tid&1;
        const int t = tb0 + r;
        float vals[64]; float ss=0.f;
        const f4* cp = (const f4*)(cosp + t*64);
        const f4* sp = (const f4*)(sinp + t*64);
        #pragma unroll
        for (int j4=0;j4<16;++j4){
            f4 cs = cp[j4], sn = sp[j4];
            #pragma unroll
            for (int u=0;u<4;++u){
                int j = j4*4+u;
                float z1 = b2f(Cs[r*132 + j]);
                float z2 = b2f(Cs[r*132 + 64 + j]);
                float zo = g ? (z2*cs[u] - z1*sn[u]) : (z1*cs[u] + z2*sn[u]);
                vals[j]=zo; ss += zo*zo;
            }
        }
        ss += __shfl_xor(ss, 1);
        float rms = rsqrtf(ss*(1.f/128.f)+EPSV);
        u16t* dst = (type==0 ? qws + ((size_t)(bb*HH+head)*TT + t)*DD
                             : kws + ((size_t)(bb*KVHN+head)*TT + t)*DD) + g*64;
        #pragma unroll
        for (int j=0;j<64;j+=8){
            u32x4 o = { pk2(vals[j]*rms,   vals[j+1]*rms), pk2(vals[j+2]*rms, vals[j+3]*rms),
                        pk2(vals[j+4]*rms, vals[j+5]*rms), pk2(vals[j+6]*rms, vals[j+7]*rms) };
            st16(dst+j, o);
        }
    }
}

// ---------------- Kernel 2: causal flash attention (MFMA, Bq=64, fixed-max softmax) ----------------
// Block = (64-query tile, h, b): 1024 blocks. Wave w owns q-rows q0+w*16..+15.
// Fragment-identity LDS for K (16 blocks) and V^T (16 blocks); Q frags from global.
__global__ __launch_bounds__(256,3) void attn_kernel(
    const u16t* __restrict__ qws, const u16t* __restrict__ kws,
    const u16t* __restrict__ vtw, u16t* __restrict__ yws)
{
    __shared__ u16t lds[20992];       // 41984 B
    u16t* Ks = lds;                   // 16 blocks x 512
    u16t* Vt = lds + 8192;            // 16 blocks x 512
    u16t* Ps = lds + 16384;           // [64][72] per-wave P slices

    const int tid = threadIdx.x;
    const int w = tid>>6, lane = tid&63, quad = lane>>4, l15 = lane&15;
    const int qti = 31 - blockIdx.x;  // long blocks dispatch first
    const int q0 = qti*64;
    const int h = blockIdx.y, b = blockIdx.z, kvh = h>>2;

    const u16t* qb = qws + ((size_t)(b*HH+h)*TT + q0)*DD;
    const u16t* kb = kws + (size_t)(b*KVHN+kvh)*TT*DD;
    const u16t* vb = vtw + (size_t)(b*KVHN+kvh)*DD*TT;

    // Q fragments straight from global (wave w: rows q0+w*16..+15)
    s16x8 qf[4];
    #pragma unroll
    for (int kq=0;kq<4;++kq)
        qf[kq] = ldf(qb + (size_t)(w*16+l15)*DD + kq*32 + quad*8);

    // staging: wave w stages K blocks (kq=w, ni=u) and V blocks bl=4w+u
    const u16t* gK[4]; u16t* lK[4];
    const u16t* gV[4]; u16t* lV[4];
    #pragma unroll
    for (int u=0;u<4;++u){
        gK[u] = kb + (size_t)(u*16 + l15)*DD + w*32 + quad*8;   // + k0*DD per iter
        lK[u] = &Ks[(w*4+u)*512 + lane*8];
        int bl = w*4+u, ks = bl>>3, n8 = bl&7;
        gV[u] = vb + (size_t)(n8*16 + l15)*TT + ks*32 + quad*8; // + k0 per iter
        lV[u] = &Vt[bl*512 + lane*8];
    }

    f32x4 o_[8];
    float l_[4];
    #pragma unroll
    for (int r=0;r<4;++r) l_[r] = 0.f;
    #pragma unroll
    for (int n8=0;n8<8;++n8)
        #pragma unroll
        for (int r=0;r<4;++r) o_[n8][r] = 0.f;

    const int nkt = qti + 1;
    const int qwbase = q0 + w*16;

    for (int kt=0; kt<nkt; ++kt){
        const int k0 = kt*64;
        __syncthreads();
        #pragma unroll
        for (int u=0;u<4;++u){
            gl16(gK[u] + (size_t)k0*DD, lK[u]);
            gl16(gV[u] + k0,            lV[u]);
        }
        __syncthreads();

        // S = Q K^T
        f32x4 s[4];
        #pragma unroll
        for (int ni=0;ni<4;++ni)
            #pragma unroll
            for (int r=0;r<4;++r) s[ni][r] = 0.f;
        #pragma unroll
        for (int kq=0;kq<4;++kq){
            s16x8 kf[4];
            #pragma unroll
            for (int ni=0;ni<4;++ni) kf[ni] = ldf(&Ks[(kq*4+ni)*512 + lane*8]);
            #pragma unroll
            for (int ni=0;ni<4;++ni)
                s[ni] = __builtin_amdgcn_mfma_f32_16x16x32_bf16(qf[kq], kf[ni], s[ni], 0,0,0);
        }

        // fixed-max softmax: p = exp(s*SCALE - MFIX); per-lane partial l
        const bool need_mask = (k0 + 63) > qwbase;
        const int qrow = qwbase + quad*4;
        #pragma unroll
        for (int ni=0;ni<4;++ni){
            const int kcol = k0 + ni*16 + l15;
            #pragma unroll
            for (int r=0;r<4;++r){
                float p = __expf(__builtin_fmaf(s[ni][r], SCALE, -MFIX));
                if (need_mask && kcol > qrow + r) p = 0.f;
                l_[r] += p;
                Ps[(w*16+quad*4+r)*72 + ni*16 + l15] = f2b(p);
            }
        }

        // O += P V  (same-wave LDS round-trip; DS ops in-order, no barrier)
        #pragma unroll
        for (int ks=0;ks<2;++ks){
            s16x8 pf = ldf(&Ps[(w*16+l15)*72 + ks*32 + quad*8]);
            #pragma unroll
            for (int n8=0;n8<8;++n8){
                s16x8 vf = ldf(&Vt[(ks*8+n8)*512 + lane*8]);
                o_[n8] = __builtin_amdgcn_mfma_f32_16x16x32_bf16(pf, vf, o_[n8], 0,0,0);
            }
        }
    }

    // epilogue: reduce l across the 16 col-lanes, normalize, store y[b][t][h*128+d]
    const int qrow = q0 + w*16 + quad*4;
    float inv[4];
    #pragma unroll
    for (int r=0;r<4;++r){
        float lt = l_[r];
        lt += __shfl_xor(lt,1,16);
        lt += __shfl_xor(lt,2,16);
        lt += __shfl_xor(lt,4,16);
        lt += __shfl_xor(lt,8,16);
        inv[r] = 1.f/lt;
    }
    #pragma unroll
    for (int n8=0;n8<8;++n8)
        #pragma unroll
        for (int r=0;r<4;++r)
            yws[((size_t)(b*TT + qrow + r))*2048 + h*DD + n8*16 + l15] = f2b(o_[n8][r]*inv[r]);
}

// ---------------- Kernel 3: output projection (MFMA, fragment-identity LDS) ----------------
__global__ __launch_bounds__(256,3) void oproj_kernel(
    const u16t* __restrict__ y, const u16t* __restrict__ wob, float* __restrict__ out)
{
    __shared__ u16t lds[8192];
    u16t* As = lds;
    u16t* Bs = lds + 4096;

    const int tid = threadIdx.x;
    const int w = tid>>6, lane = tid&63, quad = lane>>4, l15 = lane&15;
    const int wm = (w>>1)*64, wn = (w&1)*64;
    const int m0 = blockIdx.x*128;
    const int n0 = blockIdx.y*128;

    const u16t* gA0 = y + (size_t)(m0 + w*16 + l15)*CC + quad*8;
    const u16t* gA1 = y + (size_t)(m0 + 64 + w*16 + l15)*CC + quad*8;
    const u16t* gB0 = wob + (size_t)(n0 + w*16 + l15)*CC + quad*8;
    const u16t* gB1 = wob + (size_t)(n0 + 64 + w*16 + l15)*CC + quad*8;
    u16t* lA0 = &As[w*512 + lane*8];
    u16t* lA1 = &As[(w+4)*512 + lane*8];
    u16t* lB0 = &Bs[w*512 + lane*8];
    u16t* lB1 = &Bs[(w+4)*512 + lane*8];

    f32x4 acc[4][4];
    #pragma unroll
    for (int i=0;i<4;++i)
        #pragma unroll
        for (int j=0;j<4;++j)
            #pragma unroll
            for (int r=0;r<4;++r) acc[i][j][r] = 0.f;

    for (int k0=0;k0<CC;k0+=32) {
        __syncthreads();
        gl16(gA0 + k0, lA0);
        gl16(gA1 + k0, lA1);
        gl16(gB0 + k0, lB0);
        gl16(gB1 + k0, lB1);
        __syncthreads();
        s16x8 af[4], bf[4];
        #pragma unroll
        for (int mi=0;mi<4;++mi) af[mi] = ldf(&As[((w>>1)*4 + mi)*512 + lane*8]);
        #pragma unroll
        for (int ni=0;ni<4;++ni) bf[ni] = ldf(&Bs[((w&1)*4 + ni)*512 + lane*8]);
        #pragma unroll
        for (int mi=0;mi<4;++mi)
            #pragma unroll
            for (int ni=0;ni<4;++ni)
                acc[mi][ni] = __builtin_amdgcn_mfma_f32_16x16x32_bf16(af[mi], bf[ni], acc[mi][ni], 0,0,0);
    }

    #pragma unroll
    for (int mi=0;mi<4;++mi){
        const int m = m0 + wm + mi*16 + quad*4;
        #pragma unroll
        for (int ni=0;ni<4;++ni){
            const int n = n0 + wn + ni*16 + l15;
            #pragma unroll
            for (int r=0;r<4;++r)
                out[(size_t)(m+r)*CC + n] = acc[mi][ni][r];
        }
    }
}

extern "C" void kernel_launch(void* const* d_in, const int* in_sizes, int n_in,
                              void* d_out, int out_size, void* d_ws, size_t ws_size,
                              hipStream_t stream) {
    const float* x    = (const float*)d_in[0];
    const float* cosp = (const float*)d_in[1];
    const float* sinp = (const float*)d_in[2];
    const float* Wq   = (const float*)d_in[3];
    const float* Wk   = (const float*)d_in[4];
    const float* Wv   = (const float*)d_in[5];
    const float* Wo   = (const float*)d_in[6];

    u16t* ws  = (u16t*)d_ws;
    u16t* xb  = ws;                          // 8388608 elems (aliased by yws after qkv)
    u16t* wqb = xb  + 8388608;               // 4194304
    u16t* wkb = wqb + 4194304;               // 1048576
    u16t* wvb = wkb + 1048576;               // 1048576
    u16t* wob = wvb + 1048576;               // 4194304
    u16t* qws = wob + 4194304;               // 8388608
    u16t* kws = qws + 8388608;               // 2097152
    u16t* vtw = kws + 2097152;               // 2097152
    u16t* yws = xb;                          // alias: xb dead after qkv_kernel
    float* out = (float*)d_out;

    cvt_kernel<<<dim3(9216), 256, 0, stream>>>(x, Wq, Wk, Wv, Wo, xb, wqb, wkb, wvb, wob);
    qkv_kernel<<<dim3(32, 24), 256, 0, stream>>>(xb, wqb, wkb, wvb, cosp, sinp, qws, kws, vtw);
    attn_kernel<<<dim3(32, 16, 2), 256, 0, stream>>>(qws, kws, vtw, yws);
    oproj_kernel<<<dim3(32, 16), 256, 0, stream>>>(yws, wob, out);
}

// Round 7
// 398.487 us; speedup vs baseline: 1.2079x; 1.0963x over previous
//
#include <hip/hip_runtime.h>
#include <hip/hip_bf16.h>

typedef unsigned short u16t;
typedef unsigned int   u32t;
typedef float  f32x4 __attribute__((ext_vector_type(4)));
typedef short  s16x8 __attribute__((ext_vector_type(8)));
typedef unsigned int u32x4 __attribute__((ext_vector_type(4)));
typedef float  f4 __attribute__((ext_vector_type(4)));

#define BB 2
#define TT 2048
#define CC 2048
#define HH 16
#define KVHN 4
#define DD 128
#define EPSV 1.1920929e-07f
#define SCALE 0.08838834764831845f
#define MFIX 12.0f   // fixed softmax max: |q.k|*SCALE <= sqrt(128)*(1+bf16 err) < 11.5

__device__ __forceinline__ float b2f(u16t u){ union{u32t i; float f;} x; x.i=((u32t)u)<<16; return x.f; }
__device__ __forceinline__ u16t f2b(float f){ union{float f; u32t i;} x; x.f=f; u32t r = x.i + 0x7fffu + ((x.i>>16)&1u); return (u16t)(r>>16); }
__device__ __forceinline__ u32t pk2(float a, float b){
    __hip_bfloat162 h = __float22bfloat162_rn(make_float2(a,b));
    u32t r; __builtin_memcpy(&r,&h,4); return r;
}
__device__ __forceinline__ s16x8 ldf(const u16t* p){ s16x8 r; __builtin_memcpy(&r,p,16); return r; }
__device__ __forceinline__ void st16(u16t* p, u32x4 v){ __builtin_memcpy(p,&v,16); }

// async global->LDS, 16B per lane; HW LDS dest = wave-uniform base + lane*16
typedef const __attribute__((address_space(1))) unsigned int ga_u32;
typedef __attribute__((address_space(3))) unsigned int ls_u32;
__device__ __forceinline__ void gl16(const u16t* g, u16t* l) {
    __builtin_amdgcn_global_load_lds((ga_u32*)(unsigned long long)(g),
                                     (ls_u32*)(unsigned int)(unsigned long long)(l),
                                     16, 0, 0);
}

// ---------------- Kernel 0: fp32 -> bf16 conversion ----------------
// segments (in 8-elem groups): x 1048576 | wq 524288 | wk 131072 | wv 131072 | wo 524288
__global__ __launch_bounds__(256) void cvt_kernel(
    const float* __restrict__ x,  const float* __restrict__ wq,
    const float* __restrict__ wk, const float* __restrict__ wv,
    const float* __restrict__ wo,
    u16t* __restrict__ xb, u16t* __restrict__ wqb, u16t* __restrict__ wkb,
    u16t* __restrict__ wvb, u16t* __restrict__ wob)
{
    size_t g = (size_t)blockIdx.x * 256 + threadIdx.x;
    const float* src; u16t* dst; size_t off;
    if      (g < 1048576) { src = x;  dst = xb;  off = g; }
    else if (g < 1572864) { src = wq; dst = wqb; off = g - 1048576; }
    else if (g < 1703936) { src = wk; dst = wkb; off = g - 1572864; }
    else if (g < 1835008) { src = wv; dst = wvb; off = g - 1703936; }
    else                  { src = wo; dst = wob; off = g - 1835008; }
    f4 a = *(const f4*)(src + off*8);
    f4 b = *(const f4*)(src + off*8 + 4);
    u32x4 o = { pk2(a[0],a[1]), pk2(a[2],a[3]), pk2(b[0],b[1]), pk2(b[2],b[3]) };
    st16(dst + off*8, o);
}

// ---------------- Kernel 1: QKV GEMM (MFMA, dbuf gl16 staging) + RoPE + RMSNorm ----------------
// C = xb @ W^T, W rows = [Wq;Wk;Wv] bf16. Tile 128x128, BK=32, double-buffered LDS.
__global__ __launch_bounds__(256,3) void qkv_kernel(
    const u16t* __restrict__ xb, const u16t* __restrict__ wqb,
    const u16t* __restrict__ wkb, const u16t* __restrict__ wvb,
    const float* __restrict__ cosp, const float* __restrict__ sinp,
    u16t* __restrict__ qws, u16t* __restrict__ kws, u16t* __restrict__ vtw)
{
    __shared__ u16t lds[16896];   // dbuf staging 2 x (As 4096 + Bs 4096) / epilogue Cs 16896

    const int tid = threadIdx.x;
    const int w = tid>>6, lane = tid&63, quad = lane>>4, l15 = lane&15;
    const int wm = (w>>1)*64, wn = (w&1)*64;
    // XCD swizzle: same-XCD blocks (lin%8) share by => B-tile stays in that XCD's L2
    const int lin = blockIdx.x;
    const int bx = (lin>>3)&31, by = (lin&7)*3 + (lin>>8);
    const int m0 = bx*128;
    const int n0 = by*128;

    int type, head; const u16t* W;
    if (n0 < 2048)      { type=0; head = n0>>7;        W = wqb + (size_t)n0*CC; }
    else if (n0 < 2560) { type=1; head = (n0-2048)>>7; W = wkb + (size_t)(n0-2048)*CC; }
    else                { type=2; head = (n0-2560)>>7; W = wvb + (size_t)(n0-2560)*CC; }

    // staging: wave w stages A fragment blocks {w, w+4}, B blocks {w, w+4}
    const u16t* gA0 = xb + (size_t)(m0 + w*16 + l15)*CC + quad*8;
    const u16t* gA1 = xb + (size_t)(m0 + 64 + w*16 + l15)*CC + quad*8;
    const u16t* gB0 = W + (size_t)(w*16 + l15)*CC + quad*8;
    const u16t* gB1 = W + (size_t)(64 + w*16 + l15)*CC + quad*8;
    const int oA0 = w*512 + lane*8,        oA1 = (w+4)*512 + lane*8;
    const int oB0 = 4096 + w*512 + lane*8, oB1 = 4096 + (w+4)*512 + lane*8;

    f32x4 acc[4][4];
    #pragma unroll
    for (int i=0;i<4;++i)
        #pragma unroll
        for (int j=0;j<4;++j)
            #pragma unroll
            for (int r=0;r<4;++r) acc[i][j][r] = 0.f;

    // preload tile 0 into buf 0
    gl16(gA0, &lds[oA0]); gl16(gA1, &lds[oA1]);
    gl16(gB0, &lds[oB0]); gl16(gB1, &lds[oB1]);

    int it = 0;
    for (int k0=0; k0<CC; k0+=32, it^=1) {
        __syncthreads();                       // buf[it] staged (vmcnt drain), prev reads done
        if (k0+32 < CC) {                      // issue next tile into other buffer, async
            const int bo = (it^1)*8192;
            gl16(gA0 + k0+32, &lds[bo+oA0]); gl16(gA1 + k0+32, &lds[bo+oA1]);
            gl16(gB0 + k0+32, &lds[bo+oB0]); gl16(gB1 + k0+32, &lds[bo+oB1]);
        }
        const int bo = it*8192;
        s16x8 af[4], bf[4];
        #pragma unroll
        for (int mi=0;mi<4;++mi) af[mi] = ldf(&lds[bo + ((w>>1)*4 + mi)*512 + lane*8]);
        #pragma unroll
        for (int ni=0;ni<4;++ni) bf[ni] = ldf(&lds[bo + 4096 + ((w&1)*4 + ni)*512 + lane*8]);
        #pragma unroll
        for (int mi=0;mi<4;++mi)
            #pragma unroll
            for (int ni=0;ni<4;++ni)
                acc[mi][ni] = __builtin_amdgcn_mfma_f32_16x16x32_bf16(af[mi], bf[ni], acc[mi][ni], 0,0,0);
    }

    const int bb = m0>>11, tb0 = m0&2047;

    if (type==2) {
        // V: store transposed vt[b][kvh][d][t]
        u16t* vb = vtw + (size_t)(bb*KVHN+head)*DD*TT;
        #pragma unroll
        for (int mi=0;mi<4;++mi){
            int t = tb0 + wm + mi*16 + quad*4;
            #pragma unroll
            for (int ni=0;ni<4;++ni){
                int d = wn + ni*16 + l15;
                u16t o[4];
                #pragma unroll
                for (int r=0;r<4;++r) o[r] = f2b(acc[mi][ni][r]);
                __builtin_memcpy(vb + (size_t)d*TT + t, o, 8);
            }
        }
    } else {
        __syncthreads();
        u16t* Cs = lds;   // [128][132] bf16
        #pragma unroll
        for (int mi=0;mi<4;++mi)
            #pragma unroll
            for (int ni=0;ni<4;++ni)
                #pragma unroll
                for (int r=0;r<4;++r)
                    Cs[(wm+mi*16+quad*4+r)*132 + wn+ni*16+l15] = f2b(acc[mi][ni][r]);
        __syncthreads();
        const int r = tid>>1, g = tid&1;
        const int t = tb0 + r;
        float vals[64]; float ss=0.f;
        const f4* cp = (const f4*)(cosp + t*64);
        const f4* sp = (const f4*)(sinp + t*64);
        #pragma unroll
        for (int j4=0;j4<16;++j4){
            f4 cs = cp[j4], sn = sp[j4];
            #pragma unroll
            for (int u=0;u<4;++u){
                int j = j4*4+u;
                float z1 = b2f(Cs[r*132 + j]);
                float z2 = b2f(Cs[r*132 + 64 + j]);
                float zo = g ? (z2*cs[u] - z1*sn[u]) : (z1*cs[u] + z2*sn[u]);
                vals[j]=zo; ss += zo*zo;
            }
        }
        ss += __shfl_xor(ss, 1);
        float rms = rsqrtf(ss*(1.f/128.f)+EPSV);
        u16t* dst = (type==0 ? qws + ((size_t)(bb*HH+head)*TT + t)*DD
                             : kws + ((size_t)(bb*KVHN+head)*TT + t)*DD) + g*64;
        #pragma unroll
        for (int j=0;j<64;j+=8){
            u32x4 o = { pk2(vals[j]*rms,   vals[j+1]*rms), pk2(vals[j+2]*rms, vals[j+3]*rms),
                        pk2(vals[j+4]*rms, vals[j+5]*rms), pk2(vals[j+6]*rms, vals[j+7]*rms) };
            st16(dst+j, o);
        }
    }
}

// ---------------- Kernel 2: causal flash attention (MFMA, Bq=128/Bk=32, dbuf, fixed-max) ----------------
// 512 blocks; 4 waves x 32 q-rows. K/V double-buffered; one barrier per k-tile.
// Swizzle: (b,kvh) = lin%8 -> one XCD per KV group; qti paired g/(15-g) for balance.
__global__ __launch_bounds__(256,3) void attn_kernel(
    const u16t* __restrict__ qws, const u16t* __restrict__ kws,
    const u16t* __restrict__ vtw, u16t* __restrict__ yws)
{
    __shared__ u16t lds[20992];       // Ks dbuf 2x4096, Vt dbuf 2x4096, Ps [128][36]
    u16t* Ks = lds;
    u16t* Vt = lds + 8192;
    u16t* Ps = lds + 16384;

    const int tid = threadIdx.x;
    const int w = tid>>6, lane = tid&63, quad = lane>>4, l15 = lane&15;
    const int lin = blockIdx.x;
    const int b   = (lin&7)>>2;
    const int kvh = lin&3;
    const int h   = kvh*4 + ((lin>>3)&3);
    const int g   = lin>>5;
    const int qti = (g < 8) ? (15 - g) : (g - 8);
    const int q0  = qti*128;

    const u16t* qb = qws + ((size_t)(b*HH+h)*TT + q0)*DD;
    const u16t* kb = kws + (size_t)(b*KVHN+kvh)*TT*DD;
    const u16t* vb = vtw + (size_t)(b*KVHN+kvh)*DD*TT;

    // Q fragments straight from global (wave w: rows q0+w*32 .. +31)
    s16x8 qf[2][4];
    #pragma unroll
    for (int mi=0;mi<2;++mi)
        #pragma unroll
        for (int kq=0;kq<4;++kq)
            qf[mi][kq] = ldf(qb + (size_t)(w*32+mi*16+l15)*DD + kq*32 + quad*8);

    // staging: wave w stages K blocks (kq=w, ni=0/1) and V blocks n8=2w,2w+1
    const u16t* gK0 = kb + (size_t)(l15)*DD      + w*32 + quad*8;  // ni=0 rows
    const u16t* gK1 = kb + (size_t)(16 + l15)*DD + w*32 + quad*8;  // ni=1 rows
    const u16t* gV0 = vb + (size_t)((w*2+0)*16 + l15)*TT + quad*8;
    const u16t* gV1 = vb + (size_t)((w*2+1)*16 + l15)*TT + quad*8;
    const int oK0 = (w*2+0)*512 + lane*8, oK1 = (w*2+1)*512 + lane*8;
    const int oV0 = (w*2+0)*512 + lane*8, oV1 = (w*2+1)*512 + lane*8;

    f32x4 o_[2][8];
    float l_[2][4];
    #pragma unroll
    for (int mi=0;mi<2;++mi){
        #pragma unroll
        for (int r=0;r<4;++r) l_[mi][r] = 0.f;
        #pragma unroll
        for (int n8=0;n8<8;++n8)
            #pragma unroll
            for (int r=0;r<4;++r) o_[mi][n8][r] = 0.f;
    }

    const int nkt = (qti+1)*4;
    const int qwbase = q0 + w*32;

    // preload tile 0 into buf 0
    gl16(gK0, &Ks[oK0]); gl16(gK1, &Ks[oK1]);
    gl16(gV0, &Vt[oV0]); gl16(gV1, &Vt[oV1]);

    for (int kt=0; kt<nkt; ++kt){
        const int k0 = kt*32;
        const int buf = kt&1;
        __syncthreads();                       // buf[kt&1] staged; prior readers of buf^1 done
        if (kt+1 < nkt){
            const int bo = (buf^1)*4096;
            const size_t ko = (size_t)(k0+32);
            gl16(gK0 + ko*DD, &Ks[bo+oK0]); gl16(gK1 + ko*DD, &Ks[bo+oK1]);
            gl16(gV0 + ko,    &Vt[bo+oV0]); gl16(gV1 + ko,    &Vt[bo+oV1]);
        }
        if (k0 > qwbase + 31) continue;        // wave-uniform: fully masked for this wave

        const int bo = buf*4096;
        // S = Q K^T  (32 rows x 32 cols per wave)
        f32x4 s[2][2];
        #pragma unroll
        for (int mi=0;mi<2;++mi)
            #pragma unroll
            for (int ni=0;ni<2;++ni)
                #pragma unroll
                for (int r=0;r<4;++r) s[mi][ni][r] = 0.f;
        #pragma unroll
        for (int kq=0;kq<4;++kq){
            s16x8 kf0 = ldf(&Ks[bo + (kq*2+0)*512 + lane*8]);
            s16x8 kf1 = ldf(&Ks[bo + (kq*2+1)*512 + lane*8]);
            #pragma unroll
            for (int mi=0;mi<2;++mi){
                s[mi][0] = __builtin_amdgcn_mfma_f32_16x16x32_bf16(qf[mi][kq], kf0, s[mi][0], 0,0,0);
                s[mi][1] = __builtin_amdgcn_mfma_f32_16x16x32_bf16(qf[mi][kq], kf1, s[mi][1], 0,0,0);
            }
        }

        // fixed-max softmax: p = exp(s*SCALE - MFIX); per-lane partial l
        const bool need_mask = (k0 + 31) > qwbase;
        #pragma unroll
        for (int mi=0;mi<2;++mi){
            const int qrow = qwbase + mi*16 + quad*4;
            #pragma unroll
            for (int ni=0;ni<2;++ni){
                const int kcol = k0 + ni*16 + l15;
                #pragma unroll
                for (int r=0;r<4;++r){
                    float p = __expf(__builtin_fmaf(s[mi][ni][r], SCALE, -MFIX));
                    if (need_mask && kcol > qrow + r) p = 0.f;
                    l_[mi][r] += p;
                    Ps[(w*32+mi*16+quad*4+r)*36 + ni*16 + l15] = f2b(p);
                }
            }
        }

        // O += P V  (same-wave LDS round-trip; DS in-order, no barrier)
        s16x8 pf[2];
        #pragma unroll
        for (int mi=0;mi<2;++mi)
            pf[mi] = ldf(&Ps[(w*32+mi*16+l15)*36 + quad*8]);
        #pragma unroll
        for (int n8=0;n8<8;++n8){
            s16x8 vf = ldf(&Vt[bo + n8*512 + lane*8]);
            #pragma unroll
            for (int mi=0;mi<2;++mi)
                o_[mi][n8] = __builtin_amdgcn_mfma_f32_16x16x32_bf16(pf[mi], vf, o_[mi][n8], 0,0,0);
        }
    }

    // epilogue: reduce l across 16 col-lanes, normalize, store y[b][t][h*128+d]
    #pragma unroll
    for (int mi=0;mi<2;++mi){
        const int qrow = q0 + w*32 + mi*16 + quad*4;
        float inv[4];
        #pragma unroll
        for (int r=0;r<4;++r){
            float lt = l_[mi][r];
            lt += __shfl_xor(lt,1,16);
            lt += __shfl_xor(lt,2,16);
            lt += __shfl_xor(lt,4,16);
            lt += __shfl_xor(lt,8,16);
            inv[r] = 1.f/lt;
        }
        #pragma unroll
        for (int n8=0;n8<8;++n8)
            #pragma unroll
            for (int r=0;r<4;++r)
                yws[((size_t)(b*TT + qrow + r))*2048 + h*DD + n8*16 + l15] = f2b(o_[mi][n8][r]*inv[r]);
    }
}

// ---------------- Kernel 3: output projection (MFMA, dbuf gl16 staging) ----------------
__global__ __launch_bounds__(256,3) void oproj_kernel(
    const u16t* __restrict__ y, const u16t* __restrict__ wob, float* __restrict__ out)
{
    __shared__ u16t lds[16384];   // dbuf 2 x (As 4096 + Bs 4096)

    const int tid = threadIdx.x;
    const int w = tid>>6, lane = tid&63, quad = lane>>4, l15 = lane&15;
    const int wm = (w>>1)*64, wn = (w&1)*64;
    const int lin = blockIdx.x;
    const int bx = (lin>>3)&31, by = (lin&7)*2 + (lin>>8);
    const int m0 = bx*128;
    const int n0 = by*128;

    const u16t* gA0 = y + (size_t)(m0 + w*16 + l15)*CC + quad*8;
    const u16t* gA1 = y + (size_t)(m0 + 64 + w*16 + l15)*CC + quad*8;
    const u16t* gB0 = wob + (size_t)(n0 + w*16 + l15)*CC + quad*8;
    const u16t* gB1 = wob + (size_t)(n0 + 64 + w*16 + l15)*CC + quad*8;
    const int oA0 = w*512 + lane*8,        oA1 = (w+4)*512 + lane*8;
    const int oB0 = 4096 + w*512 + lane*8, oB1 = 4096 + (w+4)*512 + lane*8;

    f32x4 acc[4][4];
    #pragma unroll
    for (int i=0;i<4;++i)
        #pragma unroll
        for (int j=0;j<4;++j)
            #pragma unroll
            for (int r=0;r<4;++r) acc[i][j][r] = 0.f;

    gl16(gA0, &lds[oA0]); gl16(gA1, &lds[oA1]);
    gl16(gB0, &lds[oB0]); gl16(gB1, &lds[oB1]);

    int it = 0;
    for (int k0=0; k0<CC; k0+=32, it^=1) {
        __syncthreads();
        if (k0+32 < CC) {
            const int bo = (it^1)*8192;
            gl16(gA0 + k0+32, &lds[bo+oA0]); gl16(gA1 + k0+32, &lds[bo+oA1]);
            gl16(gB0 + k0+32, &lds[bo+oB0]); gl16(gB1 + k0+32, &lds[bo+oB1]);
        }
        const int bo = it*8192;
        s16x8 af[4], bf[4];
        #pragma unroll
        for (int mi=0;mi<4;++mi) af[mi] = ldf(&lds[bo + ((w>>1)*4 + mi)*512 + lane*8]);
        #pragma unroll
        for (int ni=0;ni<4;++ni) bf[ni] = ldf(&lds[bo + 4096 + ((w&1)*4 + ni)*512 + lane*8]);
        #pragma unroll
        for (int mi=0;mi<4;++mi)
            #pragma unroll
            for (int ni=0;ni<4;++ni)
                acc[mi][ni] = __builtin_amdgcn_mfma_f32_16x16x32_bf16(af[mi], bf[ni], acc[mi][ni], 0,0,0);
    }

    #pragma unroll
    for (int mi=0;mi<4;++mi){
        const int m = m0 + wm + mi*16 + quad*4;
        #pragma unroll
        for (int ni=0;ni<4;++ni){
            const int n = n0 + wn + ni*16 + l15;
            #pragma unroll
            for (int r=0;r<4;++r)
                out[(size_t)(m+r)*CC + n] = acc[mi][ni][r];
        }
    }
}

extern "C" void kernel_launch(void* const* d_in, const int* in_sizes, int n_in,
                              void* d_out, int out_size, void* d_ws, size_t ws_size,
                              hipStream_t stream) {
    const float* x    = (const float*)d_in[0];
    const float* cosp = (const float*)d_in[1];
    const float* sinp = (const float*)d_in[2];
    const float* Wq   = (const float*)d_in[3];
    const float* Wk   = (const float*)d_in[4];
    const float* Wv   = (const float*)d_in[5];
    const float* Wo   = (const float*)d_in[6];

    u16t* ws  = (u16t*)d_ws;
    u16t* xb  = ws;                          // 8388608 elems (aliased by yws after qkv)
    u16t* wqb = xb  + 8388608;               // 4194304
    u16t* wkb = wqb + 4194304;               // 1048576
    u16t* wvb = wkb + 1048576;               // 1048576
    u16t* wob = wvb + 1048576;               // 4194304
    u16t* qws = wob + 4194304;               // 8388608
    u16t* kws = qws + 8388608;               // 2097152
    u16t* vtw = kws + 2097152;               // 2097152
    u16t* yws = xb;                          // alias: xb dead after qkv_kernel
    float* out = (float*)d_out;

    cvt_kernel<<<dim3(9216), 256, 0, stream>>>(x, Wq, Wk, Wv, Wo, xb, wqb, wkb, wvb, wob);
    qkv_kernel<<<dim3(768), 256, 0, stream>>>(xb, wqb, wkb, wvb, cosp, sinp, qws, kws, vtw);
    attn_kernel<<<dim3(512), 256, 0, stream>>>(qws, kws, vtw, yws);
    oproj_kernel<<<dim3(512), 256, 0, stream>>>(yws, wob, out);
}